// Round 1
// baseline (654.560 us; speedup 1.0000x reference)
//
#include <hip/hip_runtime.h>
#include <cstdint>

#define NPOINTS 524288
#define NLEV 24
#define CAP 262144
#define NFEAT 2
#define HASHMUL 2531011u

__global__ __launch_bounds__(256) void permuto_kernel(
    const float* __restrict__ pos,      // [N,3]
    const float* __restrict__ lattice,  // [L,C,F]
    const float* __restrict__ shift,    // [L,3]
    const float* __restrict__ anneal,   // [L]
    const float* __restrict__ scale,    // [L]
    float* __restrict__ out)            // [N, L*F]
{
    __shared__ float s_sf0[NLEV], s_sf1[NLEV], s_sf2[NLEV];
    __shared__ float s_sh0[NLEV], s_sh1[NLEV], s_sh2[NLEV];
    __shared__ float s_an[NLEV];
    const int t = threadIdx.x;
    if (t < NLEV) {
        float sc = scale[t];
        s_sf0[t] = sc / sqrtf(2.0f);    // (0+1)*(0+2) = 2
        s_sf1[t] = sc / sqrtf(6.0f);    // (1+1)*(1+2) = 6
        s_sf2[t] = sc / sqrtf(12.0f);   // (2+1)*(2+2) = 12
        s_sh0[t] = shift[t*3+0];
        s_sh1[t] = shift[t*3+1];
        s_sh2[t] = shift[t*3+2];
        s_an[t]  = anneal[t];
    }
    __syncthreads();

    const int tid = blockIdx.x * 256 + t;
    const int n = tid / NLEV;          // point index
    const int l = tid - n * NLEV;      // level index

    const float p0 = pos[n*3+0];
    const float p1 = pos[n*3+1];
    const float p2 = pos[n*3+2];

    // cf = (p + shift) * scale_factor  (add then mul, matches JAX)
    const float cf0 = (p0 + s_sh0[l]) * s_sf0[l];
    const float cf1 = (p1 + s_sh1[l]) * s_sf1[l];
    const float cf2 = (p2 + s_sh2[l]) * s_sf2[l];

    // reverse cumsum: S[i] = sum_{j>=i} cf[j], built back-to-front like XLA
    const float S2 = cf2;
    const float S1 = cf2 + cf1;
    const float S0 = S1 + cf0;

    float E[4];
    E[0] = S0;                 // sum of all
    E[1] = S1 - 1.0f*cf0;      // S_next[0] - 1*cf0
    E[2] = S2 - 2.0f*cf1;      // S_next[1] - 2*cf1
    E[3] = 0.0f - 3.0f*cf2;    // 0 - 3*cf2

    // round each elevated coord to nearest multiple of dp1=4
    float rem0[4];
    float sumrem = 0.0f;
    #pragma unroll
    for (int i = 0; i < 4; ++i) {
        float v  = E[i] * 0.25f;           // exact (pow2)
        float up = ceilf(v)  * 4.0f;
        float dn = floorf(v) * 4.0f;
        rem0[i] = (up - E[i] < E[i] - dn) ? up : dn;
        sumrem += rem0[i];                 // exact: multiples of 4 < 2^24
    }
    const int sum_val = (int)rintf(sumrem * 0.25f);  // exact integer

    // diff (exact: close subtraction), computed BEFORE under/over fix
    float diff[4];
    #pragma unroll
    for (int i = 0; i < 4; ++i) diff[i] = E[i] - rem0[i];

    // rank[i] = #{j>i: diff[j] > diff[i]} + #{j<i: diff[j] >= diff[i]} + sum_val
    int rank[4];
    #pragma unroll
    for (int i = 0; i < 4; ++i) {
        int rk = 0;
        #pragma unroll
        for (int j = 0; j < 4; ++j) {
            if (j > i)      rk += (diff[j] >  diff[i]) ? 1 : 0;
            else if (j < i) rk += (diff[j] >= diff[i]) ? 1 : 0;
        }
        rk += sum_val;
        if (rk < 0)      { rk += 4; rem0[i] += 4.0f; }
        else if (rk > 3) { rk -= 4; rem0[i] -= 4.0f; }
        rank[i] = rk;
    }

    // delta = (E - rem0_adjusted) / 4   (exact subtraction, exact /4)
    float delta[4];
    #pragma unroll
    for (int i = 0; i < 4; ++i) delta[i] = (E[i] - rem0[i]) * 0.25f;

    // barycentric coords, literal translation of the masked-sum formulation
    float b[5];
    #pragma unroll
    for (int k = 0; k < 5; ++k) {
        float acc = 0.0f;
        #pragma unroll
        for (int i = 0; i < 4; ++i) {
            int ti = 3 - rank[i];
            float m = ((ti == k) ? 1.0f : 0.0f) - ((ti == (k-1)) ? 1.0f : 0.0f);
            acc += delta[i] * m;
        }
        b[k] = acc;
    }
    b[0] += 1.0f + b[4];

    int rem0i[4];
    #pragma unroll
    for (int i = 0; i < 4; ++i) rem0i[i] = (int)rintf(rem0[i]);  // exact

    // hash + gather + weighted sum
    const float* tbl = lattice + (size_t)l * (CAP * NFEAT);
    float o0 = 0.0f, o1 = 0.0f;
    #pragma unroll
    for (int r = 0; r < 4; ++r) {
        uint32_t h = 0u;
        #pragma unroll
        for (int i = 0; i < 3; ++i) {
            int key = rem0i[i] + r - 4 * ((rank[i] > 3 - r) ? 1 : 0);
            h = (h + (uint32_t)key) * HASHMUL;
        }
        uint32_t ix = h & (uint32_t)(CAP - 1);    // C = 2^18 -> mask
        const float2 val = *reinterpret_cast<const float2*>(tbl + (size_t)ix * 2);
        o0 += b[r] * val.x;
        o1 += b[r] * val.y;
    }

    const float an = s_an[l];
    float2 res;
    res.x = o0 * an;
    res.y = o1 * an;
    *reinterpret_cast<float2*>(out + (size_t)tid * 2) = res;
}

extern "C" void kernel_launch(void* const* d_in, const int* in_sizes, int n_in,
                              void* d_out, int out_size, void* d_ws, size_t ws_size,
                              hipStream_t stream) {
    const float* pos     = (const float*)d_in[0];
    const float* lattice = (const float*)d_in[1];
    const float* shift   = (const float*)d_in[2];
    const float* anneal  = (const float*)d_in[3];
    const float* scale   = (const float*)d_in[4];
    float* out = (float*)d_out;

    const int total = NPOINTS * NLEV;           // 12,582,912
    const int block = 256;
    const int grid  = total / block;            // 49152, divides exactly
    permuto_kernel<<<grid, block, 0, stream>>>(pos, lattice, shift, anneal, scale, out);
}

// Round 2
// 246.892 us; speedup vs baseline: 2.6512x; 2.6512x over previous
//
#include <hip/hip_runtime.h>
#include <cstdint>

#define NPOINTS 524288
#define NLEV 24
#define CAP 262144
#define NFEAT 2
#define HASHMUL 2531011u
#define BLOCKS_PER_LEVEL (NPOINTS / 256)   // 2048

// Main kernel: one block = (one level, 256 consecutive points).
// blockIdx swizzled so XCD x (= blockIdx%8) handles levels {x, x+8, x+16}
// sequentially -> each XCD's L2 holds ~one 2MB table at a time.
template <bool USE_WS>
__global__ __launch_bounds__(256) void permuto_kernel(
    const float* __restrict__ pos,      // [N,3]
    const float* __restrict__ lattice,  // [L,C,F]
    const float* __restrict__ shift,    // [L,3]
    const float* __restrict__ anneal,   // [L]
    const float* __restrict__ scale,    // [L]
    float2* __restrict__ ws,            // [L][N] float2 (level-major)
    float* __restrict__ out)            // [N, L*F] (direct fallback)
{
    const int bid  = blockIdx.x;
    const int xcd  = bid & 7;
    const int slot = bid >> 3;                 // 0..6143
    const int l    = xcd + 8 * (slot >> 11);   // slot/2048 in {0,1,2}
    const int nb   = slot & (BLOCKS_PER_LEVEL - 1);
    const int n    = (nb << 8) + threadIdx.x;  // point index

    // block-uniform level constants -> scalar regs
    const float sc  = scale[l];
    const float sf0 = sc / sqrtf(2.0f);
    const float sf1 = sc / sqrtf(6.0f);
    const float sf2 = sc / sqrtf(12.0f);
    const float sh0 = shift[l*3+0];
    const float sh1 = shift[l*3+1];
    const float sh2 = shift[l*3+2];
    const float an  = anneal[l];

    const float p0 = pos[n*3+0];
    const float p1 = pos[n*3+1];
    const float p2 = pos[n*3+2];

    const float cf0 = (p0 + sh0) * sf0;
    const float cf1 = (p1 + sh1) * sf1;
    const float cf2 = (p2 + sh2) * sf2;

    const float S2 = cf2;
    const float S1 = cf2 + cf1;
    const float S0 = S1 + cf0;

    float E[4];
    E[0] = S0;
    E[1] = S1 - 1.0f*cf0;
    E[2] = S2 - 2.0f*cf1;
    E[3] = 0.0f - 3.0f*cf2;

    float rem0[4];
    float sumrem = 0.0f;
    #pragma unroll
    for (int i = 0; i < 4; ++i) {
        float v  = E[i] * 0.25f;
        float up = ceilf(v)  * 4.0f;
        float dn = floorf(v) * 4.0f;
        rem0[i] = (up - E[i] < E[i] - dn) ? up : dn;
        sumrem += rem0[i];
    }
    const int sum_val = (int)rintf(sumrem * 0.25f);

    float diff[4];
    #pragma unroll
    for (int i = 0; i < 4; ++i) diff[i] = E[i] - rem0[i];

    int rank[4];
    #pragma unroll
    for (int i = 0; i < 4; ++i) {
        int rk = 0;
        #pragma unroll
        for (int j = 0; j < 4; ++j) {
            if (j > i)      rk += (diff[j] >  diff[i]) ? 1 : 0;
            else if (j < i) rk += (diff[j] >= diff[i]) ? 1 : 0;
        }
        rk += sum_val;
        if (rk < 0)      { rk += 4; rem0[i] += 4.0f; }
        else if (rk > 3) { rk -= 4; rem0[i] -= 4.0f; }
        rank[i] = rk;
    }

    float delta[4];
    #pragma unroll
    for (int i = 0; i < 4; ++i) delta[i] = (E[i] - rem0[i]) * 0.25f;

    float b[5];
    #pragma unroll
    for (int k = 0; k < 5; ++k) {
        float acc = 0.0f;
        #pragma unroll
        for (int i = 0; i < 4; ++i) {
            int ti = 3 - rank[i];
            float m = ((ti == k) ? 1.0f : 0.0f) - ((ti == (k-1)) ? 1.0f : 0.0f);
            acc += delta[i] * m;
        }
        b[k] = acc;
    }
    b[0] += 1.0f + b[4];

    int rem0i[4];
    #pragma unroll
    for (int i = 0; i < 4; ++i) rem0i[i] = (int)rintf(rem0[i]);

    const float* tbl = lattice + (size_t)l * (CAP * NFEAT);
    float o0 = 0.0f, o1 = 0.0f;
    #pragma unroll
    for (int r = 0; r < 4; ++r) {
        uint32_t h = 0u;
        #pragma unroll
        for (int i = 0; i < 3; ++i) {
            int key = rem0i[i] + r - 4 * ((rank[i] > 3 - r) ? 1 : 0);
            h = (h + (uint32_t)key) * HASHMUL;
        }
        uint32_t ix = h & (uint32_t)(CAP - 1);
        const float2 val = *reinterpret_cast<const float2*>(tbl + (size_t)ix * 2);
        o0 += b[r] * val.x;
        o1 += b[r] * val.y;
    }

    float2 res;
    res.x = o0 * an;
    res.y = o1 * an;
    if (USE_WS) {
        ws[(size_t)l * NPOINTS + n] = res;                 // coalesced
    } else {
        *reinterpret_cast<float2*>(out + (size_t)n * (NLEV*NFEAT) + l*NFEAT) = res;
    }
}

// Transpose [L][N] float2  ->  [N][L*2] float.  Tile: 128 points per block.
__global__ __launch_bounds__(256) void transpose_kernel(
    const float* __restrict__ ws,   // [L][N][2] as flat floats
    float* __restrict__ out)        // [N][48]
{
    __shared__ float lds[128 * 49];   // [point][48] padded to 49
    const int t  = threadIdx.x;
    const int n0 = blockIdx.x * 128;

    #pragma unroll
    for (int l = 0; l < NLEV; ++l) {
        // 256 consecutive floats = 128 points' float2 at level l
        const float v = ws[(size_t)l * (NPOINTS*2) + (size_t)n0 * 2 + t];
        const int p = t >> 1;
        const int f = t & 1;
        lds[p * 49 + l * 2 + f] = v;
    }
    __syncthreads();

    const size_t obase = (size_t)n0 * 48;
    #pragma unroll
    for (int it = 0; it < 24; ++it) {     // 128*48 / 256 = 24
        const int flat = it * 256 + t;
        const int p = flat / 48;
        const int c = flat - p * 48;
        out[obase + flat] = lds[p * 49 + c];
    }
}

extern "C" void kernel_launch(void* const* d_in, const int* in_sizes, int n_in,
                              void* d_out, int out_size, void* d_ws, size_t ws_size,
                              hipStream_t stream) {
    const float* pos     = (const float*)d_in[0];
    const float* lattice = (const float*)d_in[1];
    const float* shift   = (const float*)d_in[2];
    const float* anneal  = (const float*)d_in[3];
    const float* scale   = (const float*)d_in[4];
    float* out = (float*)d_out;

    const int grid = NLEV * BLOCKS_PER_LEVEL;   // 49152
    const size_t ws_needed = (size_t)NLEV * NPOINTS * 2 * sizeof(float);

    if (ws_size >= ws_needed) {
        float2* ws = (float2*)d_ws;
        permuto_kernel<true><<<grid, 256, 0, stream>>>(
            pos, lattice, shift, anneal, scale, ws, out);
        transpose_kernel<<<NPOINTS / 128, 256, 0, stream>>>(
            (const float*)d_ws, out);
    } else {
        permuto_kernel<false><<<grid, 256, 0, stream>>>(
            pos, lattice, shift, anneal, scale, nullptr, out);
    }
}